// Round 9
// baseline (92.578 us; speedup 1.0000x reference)
//
#include <hip/hip_runtime.h>
#include <math.h>

// Problem constants (from reference)
#define B_    16
#define H_    32
#define HKV_  8
#define G_    4      // H / HKV
#define D_    128
#define DV_   128
#define S_    8192
#define M_    64
#define BN_   64
#define KVSTRIDE (HKV_ * D_)     // 1024 floats between consecutive positions

#define CHUNK_ 16                // rows per pipeline chunk (quarter KV block)
#define NBPW_  8                 // KV blocks per WG
#define SPLIT_ (M_ / NBPW_)      // 8 partials per (b,hkv)
#define NCTOT_ (NBPW_ * BN_ / CHUNK_)   // 32 chunks per WG

// Async global->LDS, 16 B per lane: LDS dest is wave-uniform base + lane*16,
// global src is per-lane (swizzle goes on the SOURCE address).
__device__ __forceinline__ void gload_lds16(const float* gsrc, float* lds_dst) {
    __builtin_amdgcn_global_load_lds(
        (const __attribute__((address_space(1))) void*)gsrc,
        (__attribute__((address_space(3))) void*)lds_dst,
        16, 0, 0);
}

__device__ __forceinline__ float bcast_lane(float v, int srclane) {
    return __uint_as_float(__builtin_amdgcn_readlane(__float_as_uint(v), srclane));
}

// ---------------------------------------------------------------------------
// Kernel 1: R6 structure (88.7 us best) + globally SORTED fetch order.
// 1024 persistent WGs at 4 WG/CU (LDS 32 KB/WG); WG (bh, oct) takes the
// contiguous slice [oct*8, oct*8+8) of the ASCENDING-sorted 64-entry block
// list, ONE partial out. 256 threads = 4 waves; wave w = head g. XCD
// grouping: blockIdx%8 == hkv, so the 8 WGs of one (b,hkv) sweep the KV
// region in ascending page order on one XCD; duplicate ids are adjacent
// (refetch -> L1/L2 hit).
//
// Sort: lane i holds list[i]; rank_i = #{j: id_j<id_i or (==, j<i)} via 64
// readlane compares; ds_permute pushes id to lane rank -> lane l holds
// sorted[l]. Deterministic total order (ties by index).
//
// Pipeline at 16-row chunk granularity, 2 global_load_lds (1 KB each) per
// wave per K/V stage; counted vmcnt (steady 4, tail 2/0) keeps loads in
// flight across barriers — byte-identical schedule to R6.
// ---------------------------------------------------------------------------
__global__ __launch_bounds__(256)
void sfa_partial(const float* __restrict__ q,
                 const float* __restrict__ K,
                 const float* __restrict__ V,
                 const int*   __restrict__ blk_idx,
                 const int*   __restrict__ seqlens,
                 float* __restrict__ o_ws,    // [B*HKV*G*SPLIT_][DV]
                 float* __restrict__ ml_ws)   // [B*HKV*G*SPLIT_][2]
{
    __shared__ float Klds[2][CHUNK_ * D_];   // 2 x 8 KB, swizzled granules
    __shared__ float Vlds[2][CHUNK_ * DV_];  // 2 x 8 KB, linear

    const int w    = blockIdx.x;        // 0..1023
    const int hkv  = w & 7;             // == XCD id (round-robin dispatch)
    const int t    = w >> 3;            // 0..127
    const int b    = t & 15;
    const int oct  = t >> 4;            // 0..7: which sorted 8-block slice
    const int bh   = b * HKV_ + hkv;

    const int tid  = threadIdx.x;
    const int wave = tid >> 6;          // == head-in-group g
    const int lane = tid & 63;
    const int c    = lane & 3;          // 16-B granule column within 64 B
    const int jr   = lane >> 2;         // key index (16 keys per chunk)

    const int h = hkv * G_ + wave;
    // 1/sqrt(128) * log2(e): scores land directly in exp2 domain
    const float kscale = 0.08838834764831845f * 1.4426950408889634f;

    // q4[f] = q[f*16 + c*4 .. +3], pre-scaled (granule index g = f*4 + c)
    float4 q4[8];
    {
        const float* qp = q + (size_t)(b * H_ + h) * D_ + c * 4;
        #pragma unroll
        for (int f = 0; f < 8; ++f) {
            float4 tq = *(const float4*)(qp + f * 16);
            q4[f] = make_float4(tq.x * kscale, tq.y * kscale,
                                tq.z * kscale, tq.w * kscale);
        }
    }

    // ---- load full 64-entry block list and sort ascending across lanes ----
    const int id64 = blk_idx[bh * M_ + lane];
    int rank = 0;
    #pragma unroll
    for (int j = 0; j < 64; ++j) {
        const int idj = __builtin_amdgcn_readlane(id64, j);   // uniform
        rank += (idj < id64 || (idj == id64 && j < lane)) ? 1 : 0;
    }
    // push my id to lane 'rank': lane l ends up holding sorted[l]
    const int sorted = __builtin_amdgcn_ds_permute(rank << 2, id64);

    const int seqlen = seqlens[b];
    const float* Kb = K + (size_t)b * S_ * KVSTRIDE + hkv * D_;
    const float* Vb = V + (size_t)b * S_ * KVSTRIDE + hkv * D_;

    // Drain prologue loads so the counted vmcnt waits start exact.
    asm volatile("s_waitcnt vmcnt(0)" ::: "memory");

    // block id of chunk cc (4 chunks per block), uniform
    auto blkOf = [&](int cc) -> int {
        return __builtin_amdgcn_readlane(sorted, oct * NBPW_ + (cc >> 2));
    };

    // Stage one 16-row chunk (8 KB): 2 instrs/wave, 1 KB each.
    // Instr p (0..7) covers rows {2p, 2p+1}; lane -> row 2p+(lane>>5),
    // granule slot lane&31. K source granule = slot ^ (row&7) so the later
    // strided ds_read_b128 QK reads are bank-conflict-free (0 conflicts
    // measured R4-R6 with this exact layout).
    auto stageK = [&](int cc) {
        const int blk  = blkOf(cc);
        const int blkc = (blk < 0) ? 0 : blk;          // clamp: loads stay legal
        const size_t rowbase = (size_t)blkc * BN_ + (cc & 3) * CHUNK_;
        float* dst = &Klds[cc & 1][0];
        #pragma unroll
        for (int i = 0; i < 2; ++i) {
            const int p   = wave * 2 + i;              // 0..7
            const int row = 2 * p + (lane >> 5);       // 0..15
            const int g16 = lane & 31;
            const float* src = Kb + (rowbase + row) * KVSTRIDE
                                  + ((g16 ^ (row & 7)) << 2);
            gload_lds16(src, dst + p * 256);
        }
    };
    auto stageV = [&](int cc) {
        const int blk  = blkOf(cc);
        const int blkc = (blk < 0) ? 0 : blk;
        const size_t rowbase = (size_t)blkc * BN_ + (cc & 3) * CHUNK_;
        float* dst = &Vlds[cc & 1][0];
        #pragma unroll
        for (int i = 0; i < 2; ++i) {
            const int p   = wave * 2 + i;
            const int row = 2 * p + (lane >> 5);
            const int g16 = lane & 31;
            const float* src = Vb + (rowbase + row) * KVSTRIDE + (g16 << 2);
            gload_lds16(src, dst + p * 256);
        }
    };

    float m  = -INFINITY;
    float l  = 0.f;
    float o0 = 0.f, o1 = 0.f;   // output dims 2*lane, 2*lane+1 (unnormalized)

    stageK(0); stageV(0); stageK(1);

    #pragma unroll 2
    for (int cc = 0; cc < NCTOT_; ++cc) {
        const int  blk  = blkOf(cc);
        const bool bval = (blk >= 0);
        const int  pos0 = ((blk < 0) ? 0 : blk) * BN_ + (cc & 3) * CHUNK_;
        const bool last = (cc == NCTOT_ - 1);

        // ---- K[cc] ready ----
        if (last) asm volatile("s_waitcnt vmcnt(2)" ::: "memory");
        else      asm volatile("s_waitcnt vmcnt(4)" ::: "memory");
        __builtin_amdgcn_s_barrier();
        __builtin_amdgcn_sched_barrier(0);

        // ---- QK^T from LDS: 16 scores for this wave's head ----
        float s0;
        {
            const float* kr = &Klds[cc & 1][jr * D_];
            float acc = 0.f;
            #pragma unroll
            for (int f = 0; f < 8; ++f) {
                const int gg = (((f * 4 + c) ^ (jr & 7)) << 2);
                float4 k4 = *(const float4*)(kr + gg);
                acc += q4[f].x * k4.x;
                acc += q4[f].y * k4.y;
                acc += q4[f].z * k4.z;
                acc += q4[f].w * k4.w;
            }
            acc += __shfl_xor(acc, 1);
            acc += __shfl_xor(acc, 2);
            s0 = (bval && (pos0 + jr) < seqlen) ? acc : -INFINITY;
        }

        if (cc + 1 < NCTOT_) stageV(cc + 1);

        // ---- V[cc] ready ----
        if (last) asm volatile("s_waitcnt vmcnt(0)" ::: "memory");
        else      asm volatile("s_waitcnt vmcnt(4)" ::: "memory");
        __builtin_amdgcn_s_barrier();
        __builtin_amdgcn_sched_barrier(0);

        if (cc + 2 < NCTOT_) stageK(cc + 2);

        // ---- online softmax (exp2 domain) ----
        float bmax = s0;
        #pragma unroll
        for (int off = 4; off < 64; off <<= 1)
            bmax = fmaxf(bmax, __shfl_xor(bmax, off));

        const float newm = fmaxf(m, bmax);
        if (newm != -INFINITY) {        // wave-uniform; no barriers inside
            const float rr = __builtin_amdgcn_exp2f(m - newm);   // m=-inf -> 0
            const float p0 = __builtin_amdgcn_exp2f(s0 - newm);
            float ps = p0;
            #pragma unroll
            for (int off = 4; off < 64; off <<= 1)
                ps += __shfl_xor(ps, off);

            l  = l * rr + ps;
            o0 *= rr;
            o1 *= rr;
            m  = newm;

            // ---- PV from LDS: lane owns dims (2*lane, 2*lane+1) ----
            const float* vp0 = &Vlds[cc & 1][lane * 2];
            #pragma unroll
            for (int jj = 0; jj < 16; ++jj) {
                const float pj = bcast_lane(p0, jj * 4);
                const float2 v2 = *(const float2*)(vp0 + jj * DV_);
                o0 += pj * v2.x;
                o1 += pj * v2.y;
            }
        }
    }

    // ---- write the single partial for this WG ----
    const int pidx = (bh * G_ + wave) * SPLIT_ + oct;
    *(float2*)(o_ws + (size_t)pidx * DV_ + lane * 2) = make_float2(o0, o1);
    if (lane == 0)
        *(float2*)(ml_ws + pidx * 2) = make_float2(m, l);
}

// ---------------------------------------------------------------------------
// Kernel 2: combine SPLIT partials per (b, h). One wave per output row;
// lane sp holds (m,l) of partial sp, factors broadcast via readlane.
// ---------------------------------------------------------------------------
template<int SPLIT>
__global__ __launch_bounds__(64)
void sfa_reduce(const float* __restrict__ o_ws,
                const float* __restrict__ ml_ws,
                float* __restrict__ out)
{
    const int bhg  = blockIdx.x;            // == b*H + h
    const int lane = threadIdx.x;

    float mi = -INFINITY, li = 0.f;
    if (lane < SPLIT) {
        const float2 t = ((const float2*)ml_ws)[bhg * SPLIT + lane];
        mi = t.x; li = t.y;
    }
    float mfull = mi;
    #pragma unroll
    for (int off = 1; off < 64; off <<= 1)
        mfull = fmaxf(mfull, __shfl_xor(mfull, off));

    const float f = (mi == -INFINITY) ? 0.f
                  : __builtin_amdgcn_exp2f(mi - mfull);
    float L = li * f;
    #pragma unroll
    for (int off = 1; off < 64; off <<= 1)
        L += __shfl_xor(L, off);

    float o0 = 0.f, o1 = 0.f;
    #pragma unroll
    for (int i = 0; i < SPLIT; ++i) {
        const float fi = bcast_lane(f, i);  // uniform
        if (fi != 0.f) {
            const float* op = o_ws + (size_t)(bhg * SPLIT + i) * DV_ + lane * 2;
            o0 += fi * op[0];
            o1 += fi * op[1];
        }
    }
    const float inv = (L > 0.f) ? (1.f / L) : 0.f;
    out[(size_t)bhg * DV_ + lane * 2]     = o0 * inv;
    out[(size_t)bhg * DV_ + lane * 2 + 1] = o1 * inv;
}

// ---------------------------------------------------------------------------
extern "C" void kernel_launch(void* const* d_in, const int* in_sizes, int n_in,
                              void* d_out, int out_size, void* d_ws, size_t ws_size,
                              hipStream_t stream) {
    const float* q    = (const float*)d_in[0];
    const float* K    = (const float*)d_in[1];
    const float* V    = (const float*)d_in[2];
    const int*   bidx = (const int*)d_in[3];
    const int*   slen = (const int*)d_in[4];
    // d_in[5] = block_size (==BN_), compile-time constant here

    // ws need: 16*8*4*8*128 floats (2.1 MB) + 32 KB of (m,l)
    float* o_ws  = (float*)d_ws;
    float* ml_ws = o_ws + (size_t)B_ * HKV_ * G_ * SPLIT_ * DV_;

    sfa_partial<<<B_ * HKV_ * SPLIT_, 256, 0, stream>>>(
        q, K, V, bidx, slen, o_ws, ml_ws);

    sfa_reduce<SPLIT_><<<B_ * H_, 64, 0, stream>>>(o_ws, ml_ws, (float*)d_out);
}

// Round 10
// 88.750 us; speedup vs baseline: 1.0431x; 1.0431x over previous
//
#include <hip/hip_runtime.h>
#include <math.h>

// Problem constants (from reference)
#define B_    16
#define H_    32
#define HKV_  8
#define G_    4      // H / HKV
#define D_    128
#define DV_   128
#define S_    8192
#define M_    64
#define BN_   64
#define KVSTRIDE (HKV_ * D_)     // 1024 floats between consecutive positions

#define CHUNK_ 16                // rows per pipeline chunk (quarter KV block)
#define NBPW_  8                 // KV blocks per WG
#define SPLIT_ (M_ / NBPW_)      // 8 partials per (b,hkv)
#define NCTOT_ (NBPW_ * BN_ / CHUNK_)   // 32 chunks per WG

// Async global->LDS, 16 B per lane: LDS dest is wave-uniform base + lane*16,
// global src is per-lane (swizzle goes on the SOURCE address).
__device__ __forceinline__ void gload_lds16(const float* gsrc, float* lds_dst) {
    __builtin_amdgcn_global_load_lds(
        (const __attribute__((address_space(1))) void*)gsrc,
        (__attribute__((address_space(3))) void*)lds_dst,
        16, 0, 0);
}

__device__ __forceinline__ float bcast_lane(float v, int srclane) {
    return __uint_as_float(__builtin_amdgcn_readlane(__float_as_uint(v), srclane));
}

// ---------------------------------------------------------------------------
// FINAL (= R6, best measured 88.7 us): 1024 persistent WGs at 4 WG/CU
// (LDS 32 KB/WG). Each WG: one (b,hkv), 8 consecutive blocks (oct), ONE
// partial out (online softmax continues across all 8 blocks). 256 threads =
// 4 waves; wave w = head g. XCD grouping: blockIdx%8 == hkv.
//
// Structure findings (R1-R9): coalescing floor layout (16 lines/instr QK,
// 8 lines/instr V), LDS staging shared by 4 GQA heads, counted-vmcnt
// software pipeline (steady 4, tail 2/0, loads in flight across barriers).
// Swept flat: sorted order, dedup (+mult fold), deeper persistence, fused
// reduce (regressed: device fences thrash non-coherent per-XCD L2).
// Ceiling: ~4.3 TB/s effective read BW == DRAM activate limit for the
// layout's 512 B-per-4 KB-stride gather (streaming fills: 6.6 TB/s).
// ---------------------------------------------------------------------------
__global__ __launch_bounds__(256)
void sfa_partial(const float* __restrict__ q,
                 const float* __restrict__ K,
                 const float* __restrict__ V,
                 const int*   __restrict__ blk_idx,
                 const int*   __restrict__ seqlens,
                 float* __restrict__ o_ws,    // [B*HKV*G*SPLIT_][DV]
                 float* __restrict__ ml_ws)   // [B*HKV*G*SPLIT_][2]
{
    __shared__ float Klds[2][CHUNK_ * D_];   // 2 x 8 KB, swizzled granules
    __shared__ float Vlds[2][CHUNK_ * DV_];  // 2 x 8 KB, linear

    const int w    = blockIdx.x;        // 0..1023
    const int hkv  = w & 7;             // == XCD id (round-robin dispatch)
    const int t    = w >> 3;            // 0..127
    const int b    = t & 15;
    const int oct  = t >> 4;            // 0..7: which 8-block span
    const int bh   = b * HKV_ + hkv;

    const int tid  = threadIdx.x;
    const int wave = tid >> 6;          // == head-in-group g
    const int lane = tid & 63;
    const int c    = lane & 3;          // 16-B granule column within 64 B
    const int jr   = lane >> 2;         // key index (16 keys per chunk)

    const int h = hkv * G_ + wave;
    // 1/sqrt(128) * log2(e): scores land directly in exp2 domain
    const float kscale = 0.08838834764831845f * 1.4426950408889634f;

    // q4[f] = q[f*16 + c*4 .. +3], pre-scaled (granule index g = f*4 + c)
    float4 q4[8];
    {
        const float* qp = q + (size_t)(b * H_ + h) * D_ + c * 4;
        #pragma unroll
        for (int f = 0; f < 8; ++f) {
            float4 tq = *(const float4*)(qp + f * 16);
            q4[f] = make_float4(tq.x * kscale, tq.y * kscale,
                                tq.z * kscale, tq.w * kscale);
        }
    }

    // 8 block ids parked in lanes 0-7
    int vblk = 0;
    if (lane < NBPW_) vblk = blk_idx[bh * M_ + oct * NBPW_ + lane];

    const int seqlen = seqlens[b];
    const float* Kb = K + (size_t)b * S_ * KVSTRIDE + hkv * D_;
    const float* Vb = V + (size_t)b * S_ * KVSTRIDE + hkv * D_;

    // Drain prologue loads so the counted vmcnt waits start exact.
    asm volatile("s_waitcnt vmcnt(0)" ::: "memory");

    // Stage one 16-row chunk (8 KB): 2 instrs/wave, 1 KB each.
    // Instr p (0..7) covers rows {2p, 2p+1}; lane -> row 2p+(lane>>5),
    // granule slot lane&31. K source granule = slot ^ (row&7) so the later
    // strided ds_read_b128 QK reads are bank-conflict-free (0 conflicts
    // measured R4-R6 with this exact layout).
    auto stageK = [&](int cc, int blk) {
        const int blkc = (blk < 0) ? 0 : blk;          // clamp: loads stay legal
        const size_t rowbase = (size_t)blkc * BN_ + (cc & 3) * CHUNK_;
        float* dst = &Klds[cc & 1][0];
        #pragma unroll
        for (int i = 0; i < 2; ++i) {
            const int p   = wave * 2 + i;              // 0..7
            const int row = 2 * p + (lane >> 5);       // 0..15
            const int g16 = lane & 31;
            const float* src = Kb + (rowbase + row) * KVSTRIDE
                                  + ((g16 ^ (row & 7)) << 2);
            gload_lds16(src, dst + p * 256);
        }
    };
    auto stageV = [&](int cc, int blk) {
        const int blkc = (blk < 0) ? 0 : blk;
        const size_t rowbase = (size_t)blkc * BN_ + (cc & 3) * CHUNK_;
        float* dst = &Vlds[cc & 1][0];
        #pragma unroll
        for (int i = 0; i < 2; ++i) {
            const int p   = wave * 2 + i;
            const int row = 2 * p + (lane >> 5);
            const int g16 = lane & 31;
            const float* src = Vb + (rowbase + row) * KVSTRIDE + (g16 << 2);
            gload_lds16(src, dst + p * 256);
        }
    };
    // block id of chunk cc (4 chunks per block), uniform
    auto blkOf = [&](int cc) -> int {
        return __builtin_amdgcn_readlane(vblk, cc >> 2);
    };

    float m  = -INFINITY;
    float l  = 0.f;
    float o0 = 0.f, o1 = 0.f;   // output dims 2*lane, 2*lane+1 (unnormalized)

    stageK(0, blkOf(0));
    stageV(0, blkOf(0));
    stageK(1, blkOf(1));

    #pragma unroll 2
    for (int cc = 0; cc < NCTOT_; ++cc) {
        const int  blk  = blkOf(cc);
        const bool bval = (blk >= 0);
        const int  pos0 = ((blk < 0) ? 0 : blk) * BN_ + (cc & 3) * CHUNK_;
        const bool last = (cc == NCTOT_ - 1);

        // ---- K[cc] ready ----
        if (last) asm volatile("s_waitcnt vmcnt(2)" ::: "memory");
        else      asm volatile("s_waitcnt vmcnt(4)" ::: "memory");
        __builtin_amdgcn_s_barrier();
        __builtin_amdgcn_sched_barrier(0);

        // ---- QK^T from LDS: 16 scores for this wave's head ----
        float s0;
        {
            const float* kr = &Klds[cc & 1][jr * D_];
            float acc = 0.f;
            #pragma unroll
            for (int f = 0; f < 8; ++f) {
                const int gg = (((f * 4 + c) ^ (jr & 7)) << 2);
                float4 k4 = *(const float4*)(kr + gg);
                acc += q4[f].x * k4.x;
                acc += q4[f].y * k4.y;
                acc += q4[f].z * k4.z;
                acc += q4[f].w * k4.w;
            }
            acc += __shfl_xor(acc, 1);
            acc += __shfl_xor(acc, 2);
            s0 = (bval && (pos0 + jr) < seqlen) ? acc : -INFINITY;
        }

        if (cc + 1 < NCTOT_) stageV(cc + 1, blkOf(cc + 1));

        // ---- V[cc] ready ----
        if (last) asm volatile("s_waitcnt vmcnt(0)" ::: "memory");
        else      asm volatile("s_waitcnt vmcnt(4)" ::: "memory");
        __builtin_amdgcn_s_barrier();
        __builtin_amdgcn_sched_barrier(0);

        if (cc + 2 < NCTOT_) stageK(cc + 2, blkOf(cc + 2));

        // ---- online softmax (exp2 domain) ----
        float bmax = s0;
        #pragma unroll
        for (int off = 4; off < 64; off <<= 1)
            bmax = fmaxf(bmax, __shfl_xor(bmax, off));

        const float newm = fmaxf(m, bmax);
        if (newm != -INFINITY) {        // wave-uniform; no barriers inside
            const float rr = __builtin_amdgcn_exp2f(m - newm);   // m=-inf -> 0
            const float p0 = __builtin_amdgcn_exp2f(s0 - newm);
            float ps = p0;
            #pragma unroll
            for (int off = 4; off < 64; off <<= 1)
                ps += __shfl_xor(ps, off);

            l  = l * rr + ps;
            o0 *= rr;
            o1 *= rr;
            m  = newm;

            // ---- PV from LDS: lane owns dims (2*lane, 2*lane+1) ----
            const float* vp0 = &Vlds[cc & 1][lane * 2];
            #pragma unroll
            for (int jj = 0; jj < 16; ++jj) {
                const float pj = bcast_lane(p0, jj * 4);
                const float2 v2 = *(const float2*)(vp0 + jj * DV_);
                o0 += pj * v2.x;
                o1 += pj * v2.y;
            }
        }
    }

    // ---- write the single partial for this WG ----
    const int pidx = (bh * G_ + wave) * SPLIT_ + oct;
    *(float2*)(o_ws + (size_t)pidx * DV_ + lane * 2) = make_float2(o0, o1);
    if (lane == 0)
        *(float2*)(ml_ws + pidx * 2) = make_float2(m, l);
}

// ---------------------------------------------------------------------------
// Kernel 2: combine SPLIT partials per (b, h). One wave per output row;
// lane sp holds (m,l) of partial sp, factors broadcast via readlane.
// ---------------------------------------------------------------------------
template<int SPLIT>
__global__ __launch_bounds__(64)
void sfa_reduce(const float* __restrict__ o_ws,
                const float* __restrict__ ml_ws,
                float* __restrict__ out)
{
    const int bhg  = blockIdx.x;            // == b*H + h
    const int lane = threadIdx.x;

    float mi = -INFINITY, li = 0.f;
    if (lane < SPLIT) {
        const float2 t = ((const float2*)ml_ws)[bhg * SPLIT + lane];
        mi = t.x; li = t.y;
    }
    float mfull = mi;
    #pragma unroll
    for (int off = 1; off < 64; off <<= 1)
        mfull = fmaxf(mfull, __shfl_xor(mfull, off));

    const float f = (mi == -INFINITY) ? 0.f
                  : __builtin_amdgcn_exp2f(mi - mfull);
    float L = li * f;
    #pragma unroll
    for (int off = 1; off < 64; off <<= 1)
        L += __shfl_xor(L, off);

    float o0 = 0.f, o1 = 0.f;
    #pragma unroll
    for (int i = 0; i < SPLIT; ++i) {
        const float fi = bcast_lane(f, i);  // uniform
        if (fi != 0.f) {
            const float* op = o_ws + (size_t)(bhg * SPLIT + i) * DV_ + lane * 2;
            o0 += fi * op[0];
            o1 += fi * op[1];
        }
    }
    const float inv = (L > 0.f) ? (1.f / L) : 0.f;
    out[(size_t)bhg * DV_ + lane * 2]     = o0 * inv;
    out[(size_t)bhg * DV_ + lane * 2 + 1] = o1 * inv;
}

// ---------------------------------------------------------------------------
extern "C" void kernel_launch(void* const* d_in, const int* in_sizes, int n_in,
                              void* d_out, int out_size, void* d_ws, size_t ws_size,
                              hipStream_t stream) {
    const float* q    = (const float*)d_in[0];
    const float* K    = (const float*)d_in[1];
    const float* V    = (const float*)d_in[2];
    const int*   bidx = (const int*)d_in[3];
    const int*   slen = (const int*)d_in[4];
    // d_in[5] = block_size (==BN_), compile-time constant here

    // ws need: 16*8*4*8*128 floats (2.1 MB) + 32 KB of (m,l)
    float* o_ws  = (float*)d_ws;
    float* ml_ws = o_ws + (size_t)B_ * HKV_ * G_ * SPLIT_ * DV_;

    sfa_partial<<<B_ * HKV_ * SPLIT_, 256, 0, stream>>>(
        q, K, V, bidx, slen, o_ws, ml_ws);

    sfa_reduce<SPLIT_><<<B_ * H_, 64, 0, stream>>>(o_ws, ml_ws, (float*)d_out);
}